// Round 24
// baseline (113.714 us; speedup 1.0000x reference)
//
#include <hip/hip_runtime.h>
#include <hip/hip_bf16.h>
#include <math.h>

#define TSEQ 2048
#define CDIM 1024
#define NHEADS 16
#define DHEAD 64
#define BSZ 2
#define MROWS (BSZ * TSEQ)  // 4096
#define SCALE_Q 0.18033688f  // 0.125 * log2(e): softmax becomes exp2(s)

typedef __attribute__((ext_vector_type(8))) short short8;
typedef __attribute__((ext_vector_type(4))) short short4v;
typedef __attribute__((ext_vector_type(4))) float f32x4;

__device__ inline f32x4 mfma16(short8 a, short8 b, f32x4 c) {
    return __builtin_amdgcn_mfma_f32_16x16x32_bf16(a, b, c, 0, 0, 0);
}

__device__ inline short f2bf(float f) {
    __hip_bfloat16 h = __float2bfloat16(f);
    return __builtin_bit_cast(short, h);
}

__device__ inline void gl_lds16(const short* g, short* l) {
    __builtin_amdgcn_global_load_lds(
        (const __attribute__((address_space(1))) void*)g,
        (__attribute__((address_space(3))) void*)l, 16, 0, 0);
}

// ---------------------------------------------------------------------------
// conv f32 -> bf16, 8 elems/thread (x only; fallback path).
// ---------------------------------------------------------------------------
__global__ __launch_bounds__(256) void convx_kernel(const float* __restrict__ x,
                                                    short* __restrict__ xb) {
    size_t off = (size_t)(blockIdx.x * 256 + threadIdx.x) * 8;
    float4 a = *(const float4*)(x + off);
    float4 b = *(const float4*)(x + off + 4);
    short8 h;
    h[0] = f2bf(a.x); h[1] = f2bf(a.y); h[2] = f2bf(a.z); h[3] = f2bf(a.w);
    h[4] = f2bf(b.x); h[5] = f2bf(b.y); h[6] = f2bf(b.z); h[7] = f2bf(b.w);
    *(short8*)(xb + off) = h;
}

// conv x (4M) + Wq/Wk/Wv/Wp (1M each) -> bf16 in ONE launch (big-ws path).
__global__ __launch_bounds__(256) void conv5_kernel(
    const float* __restrict__ x, const float* __restrict__ swq,
    const float* __restrict__ swk, const float* __restrict__ swv,
    const float* __restrict__ swp, short* __restrict__ xb,
    short* __restrict__ wqb, short* __restrict__ wkb,
    short* __restrict__ wvb, short* __restrict__ wpb) {
    int chunk = blockIdx.x >> 9;               // 0..7 (512 blocks per 1M elems)
    size_t off = (size_t)((blockIdx.x & 511) * 256 + threadIdx.x) * 8;
    const float* s;
    short* d;
    if (chunk < 4)      { s = x + (size_t)chunk * 1048576; d = xb + (size_t)chunk * 1048576; }
    else if (chunk == 4){ s = swq; d = wqb; }
    else if (chunk == 5){ s = swk; d = wkb; }
    else if (chunk == 6){ s = swv; d = wvb; }
    else                { s = swp; d = wpb; }
    float4 a = *(const float4*)(s + off);
    float4 b = *(const float4*)(s + off + 4);
    short8 h;
    h[0] = f2bf(a.x); h[1] = f2bf(a.y); h[2] = f2bf(a.z); h[3] = f2bf(a.w);
    h[4] = f2bf(b.x); h[5] = f2bf(b.y); h[6] = f2bf(b.z); h[7] = f2bf(b.w);
    *(short8*)(d + off) = h;
}

// ---------------------------------------------------------------------------
// Fused QKV GEMM, gl_lds path (m97 structure, frozen).
// ---------------------------------------------------------------------------
__global__ __launch_bounds__(256, 3) void gemm_qkv_g(
    const short* __restrict__ xb, const short* __restrict__ wqb,
    const short* __restrict__ wkb, const short* __restrict__ wvb,
    const float* __restrict__ bq, const float* __restrict__ bk,
    const float* __restrict__ bv, short* __restrict__ qws,
    short* __restrict__ kws, short* __restrict__ vtws) {
    __shared__ __attribute__((aligned(16))) short a_lds[128 * 64];
    __shared__ __attribute__((aligned(16))) short b_lds[128 * 64];

    const int tid = threadIdx.x;
    const int lane = tid & 63;
    const int wv = tid >> 6;
    const int wr = wv >> 1, wc = wv & 1;
    const int l15 = lane & 15, l4 = lane >> 4;
    const int mbase = blockIdx.x * 128;
    const int which = blockIdx.y >> 3;
    const int nbase = (blockIdx.y & 7) * 128;
    const short* Wb = which == 0 ? wqb : (which == 1 ? wkb : wvb);
    const float* bias = which == 0 ? bq : (which == 1 ? bk : bv);

    f32x4 acc[4][4];
#pragma unroll
    for (int i = 0; i < 4; ++i)
#pragma unroll
        for (int j = 0; j < 4; ++j) acc[i][j] = f32x4{0.f, 0.f, 0.f, 0.f};

    const int srow = tid >> 3;
    const int gcol = (tid & 7) ^ (srow & 7);
    const short* asrc = xb + (size_t)(mbase + srow) * CDIM + gcol * 8;
    const short* bsrc = Wb + (size_t)(nbase + srow) * CDIM + gcol * 8;
    short* adst = &a_lds[tid * 8];
    short* bdst = &b_lds[tid * 8];

    for (int k0 = 0; k0 < CDIM; k0 += 64) {
        __syncthreads();
#pragma unroll
        for (int it = 0; it < 4; ++it) {
            gl_lds16(asrc + (size_t)(it * 32) * CDIM + k0, adst + it * 2048);
            gl_lds16(bsrc + (size_t)(it * 32) * CDIM + k0, bdst + it * 2048);
        }
        __syncthreads();

#pragma unroll
        for (int kk = 0; kk < 2; ++kk) {
            short8 af[4], bfr[4];
#pragma unroll
            for (int i = 0; i < 4; ++i) {
                int R = wr * 64 + i * 16 + l15;
                af[i] = *(const short8*)&a_lds[R * 64 + ((kk * 4 + l4) ^ (R & 7)) * 8];
            }
#pragma unroll
            for (int j = 0; j < 4; ++j) {
                int R = wc * 64 + j * 16 + l15;
                bfr[j] = *(const short8*)&b_lds[R * 64 + ((kk * 4 + l4) ^ (R & 7)) * 8];
            }
#pragma unroll
            for (int i = 0; i < 4; ++i)
#pragma unroll
                for (int j = 0; j < 4; ++j)
                    acc[i][j] = mfma16(af[i], bfr[j], acc[i][j]);
        }
    }

    if (which < 2) {
        short* dst = which == 0 ? qws : kws;
        const float scale = which == 0 ? SCALE_Q : 1.0f;
#pragma unroll
        for (int i = 0; i < 4; ++i) {
            int mrow = mbase + wr * 64 + i * 16 + l4 * 4;
#pragma unroll
            for (int j = 0; j < 4; ++j) {
                int o = nbase + wc * 64 + j * 16 + l15;
                int n = o >> 6, d = o & 63;
                float bval = bias[o];
#pragma unroll
                for (int r = 0; r < 4; ++r) {
                    int mm = mrow + r;
                    int bb = mm >> 11;
                    int t = mm & (TSEQ - 1);
                    dst[(((size_t)bb * NHEADS + n) * TSEQ + t) * DHEAD + d] =
                        f2bf((acc[i][j][r] + bval) * scale);
                }
            }
        }
    } else {
#pragma unroll
        for (int i = 0; i < 4; ++i) {
            int mrow = mbase + wr * 64 + i * 16 + l4 * 4;
            int bb = mrow >> 11;
            int t = mrow & (TSEQ - 1);
#pragma unroll
            for (int j = 0; j < 4; ++j) {
                int o = nbase + wc * 64 + j * 16 + l15;
                int n = o >> 6, d = o & 63;
                float bval = bias[o];
                short4v h4;
#pragma unroll
                for (int r = 0; r < 4; ++r) h4[r] = f2bf(acc[i][j][r] + bval);
                *(short4v*)&vtws[(((size_t)bb * NHEADS + n) * DHEAD + d) * TSEQ + t] = h4;
            }
        }
    }
}

// ---------------------------------------------------------------------------
// Fused QKV GEMM, fallback path (r18-proven): f32 weights, reg staging.
// ---------------------------------------------------------------------------
__global__ __launch_bounds__(256, 3) void gemm_qkv(
    const short* __restrict__ xb, const float* __restrict__ Wq,
    const float* __restrict__ Wk, const float* __restrict__ Wv,
    const float* __restrict__ bq, const float* __restrict__ bk,
    const float* __restrict__ bv, short* __restrict__ qws,
    short* __restrict__ kws, short* __restrict__ vtws) {
    __shared__ __attribute__((aligned(16))) short a_lds[128][72];
    __shared__ __attribute__((aligned(16))) short b_lds[128][72];

    const int tid = threadIdx.x;
    const int lane = tid & 63;
    const int wv = tid >> 6;
    const int wr = wv >> 1, wc = wv & 1;
    const int l15 = lane & 15, l4 = lane >> 4;
    const int mbase = blockIdx.x * 128;
    const int which = blockIdx.y >> 3;
    const int nbase = (blockIdx.y & 7) * 128;
    const float* Wf = which == 0 ? Wq : (which == 1 ? Wk : Wv);
    const float* bias = which == 0 ? bq : (which == 1 ? bk : bv);

    f32x4 acc[4][4];
#pragma unroll
    for (int i = 0; i < 4; ++i)
#pragma unroll
        for (int j = 0; j < 4; ++j) acc[i][j] = f32x4{0.f, 0.f, 0.f, 0.f};

    const int ar = tid >> 3;
    const int ag = (tid & 7) * 8;
    const int br = tid >> 4;
    const int bg = (tid & 15) * 4;
    const short* aptr = xb + (size_t)(mbase + ar) * CDIM + ag;
    const float* bptr = Wf + (size_t)(nbase + br) * CDIM + bg;

    short8 apre[4];
    float4 bpre[8];
#pragma unroll
    for (int it = 0; it < 4; ++it)
        apre[it] = *(const short8*)(aptr + (size_t)(32 * it) * CDIM);
#pragma unroll
    for (int it = 0; it < 8; ++it)
        bpre[it] = *(const float4*)(bptr + (size_t)(16 * it) * CDIM);

    for (int k0 = 0; k0 < CDIM; k0 += 64) {
        __syncthreads();
#pragma unroll
        for (int it = 0; it < 4; ++it)
            *(short8*)&a_lds[ar + 32 * it][ag] = apre[it];
#pragma unroll
        for (int it = 0; it < 8; ++it) {
            short4v h;
            h.x = f2bf(bpre[it].x); h.y = f2bf(bpre[it].y);
            h.z = f2bf(bpre[it].z); h.w = f2bf(bpre[it].w);
            *(short4v*)&b_lds[br + 16 * it][bg] = h;
        }
        __syncthreads();
        if (k0 + 64 < CDIM) {
#pragma unroll
            for (int it = 0; it < 4; ++it)
                apre[it] = *(const short8*)(aptr + (size_t)(32 * it) * CDIM + k0 + 64);
#pragma unroll
            for (int it = 0; it < 8; ++it)
                bpre[it] = *(const float4*)(bptr + (size_t)(16 * it) * CDIM + k0 + 64);
        }

#pragma unroll
        for (int kk = 0; kk < 2; ++kk) {
            short8 af[4], bfr[4];
#pragma unroll
            for (int i = 0; i < 4; ++i)
                af[i] = *(const short8*)&a_lds[wr * 64 + i * 16 + l15][kk * 32 + l4 * 8];
#pragma unroll
            for (int j = 0; j < 4; ++j)
                bfr[j] = *(const short8*)&b_lds[wc * 64 + j * 16 + l15][kk * 32 + l4 * 8];
#pragma unroll
            for (int i = 0; i < 4; ++i)
#pragma unroll
                for (int j = 0; j < 4; ++j)
                    acc[i][j] = mfma16(af[i], bfr[j], acc[i][j]);
        }
    }

    if (which < 2) {
        short* dst = which == 0 ? qws : kws;
        const float scale = which == 0 ? SCALE_Q : 1.0f;
#pragma unroll
        for (int i = 0; i < 4; ++i) {
            int mrow = mbase + wr * 64 + i * 16 + l4 * 4;
#pragma unroll
            for (int j = 0; j < 4; ++j) {
                int o = nbase + wc * 64 + j * 16 + l15;
                int n = o >> 6, d = o & 63;
                float bval = bias[o];
#pragma unroll
                for (int r = 0; r < 4; ++r) {
                    int mm = mrow + r;
                    int bb = mm >> 11;
                    int t = mm & (TSEQ - 1);
                    dst[(((size_t)bb * NHEADS + n) * TSEQ + t) * DHEAD + d] =
                        f2bf((acc[i][j][r] + bval) * scale);
                }
            }
        }
    } else {
#pragma unroll
        for (int i = 0; i < 4; ++i) {
            int mrow = mbase + wr * 64 + i * 16 + l4 * 4;
            int bb = mrow >> 11;
            int t = mrow & (TSEQ - 1);
#pragma unroll
            for (int j = 0; j < 4; ++j) {
                int o = nbase + wc * 64 + j * 16 + l15;
                int n = o >> 6, d = o & 63;
                float bval = bias[o];
                short4v h4;
#pragma unroll
                for (int r = 0; r < 4; ++r) h4[r] = f2bf(acc[i][j][r] + bval);
                *(short4v*)&vtws[(((size_t)bb * NHEADS + n) * DHEAD + d) * TSEQ + t] = h4;
            }
        }
    }
}

// ---------------------------------------------------------------------------
// Output projection GEMM, gl_lds path (frozen from r22).
// ---------------------------------------------------------------------------
__global__ __launch_bounds__(256) void gemm_p_g(
    const short* __restrict__ attn, const short* __restrict__ wpb,
    const float* __restrict__ bp, float* __restrict__ out) {
    __shared__ __attribute__((aligned(16))) short a_lds[64 * 64];
    __shared__ __attribute__((aligned(16))) short b_lds[128 * 64];

    const int tid = threadIdx.x;
    const int lane = tid & 63;
    const int wv = tid >> 6;
    const int wr = wv >> 1, wc = wv & 1;
    const int l15 = lane & 15, l4 = lane >> 4;
    const int mbase = blockIdx.x * 64;
    const int nbase = blockIdx.y * 128;

    f32x4 acc[2][4];
#pragma unroll
    for (int i = 0; i < 2; ++i)
#pragma unroll
        for (int j = 0; j < 4; ++j) acc[i][j] = f32x4{0.f, 0.f, 0.f, 0.f};

    const int srow = tid >> 3;
    const int gcol = (tid & 7) ^ (srow & 7);
    const short* asrc = attn + (size_t)(mbase + srow) * CDIM + gcol * 8;
    const short* bsrc = wpb + (size_t)(nbase + srow) * CDIM + gcol * 8;
    short* adst = &a_lds[tid * 8];
    short* bdst = &b_lds[tid * 8];

    for (int k0 = 0; k0 < CDIM; k0 += 64) {
        __syncthreads();
#pragma unroll
        for (int it = 0; it < 2; ++it)
            gl_lds16(asrc + (size_t)(it * 32) * CDIM + k0, adst + it * 2048);
#pragma unroll
        for (int it = 0; it < 4; ++it)
            gl_lds16(bsrc + (size_t)(it * 32) * CDIM + k0, bdst + it * 2048);
        __syncthreads();

#pragma unroll
        for (int kk = 0; kk < 2; ++kk) {
            short8 af[2], bfr[4];
#pragma unroll
            for (int i = 0; i < 2; ++i) {
                int R = wr * 32 + i * 16 + l15;
                af[i] = *(const short8*)&a_lds[R * 64 + ((kk * 4 + l4) ^ (R & 7)) * 8];
            }
#pragma unroll
            for (int j = 0; j < 4; ++j) {
                int R = wc * 64 + j * 16 + l15;
                bfr[j] = *(const short8*)&b_lds[R * 64 + ((kk * 4 + l4) ^ (R & 7)) * 8];
            }
#pragma unroll
            for (int i = 0; i < 2; ++i)
#pragma unroll
                for (int j = 0; j < 4; ++j)
                    acc[i][j] = mfma16(af[i], bfr[j], acc[i][j]);
        }
    }

#pragma unroll
    for (int i = 0; i < 2; ++i) {
        int mrow = mbase + wr * 32 + i * 16 + l4 * 4;
#pragma unroll
        for (int j = 0; j < 4; ++j) {
            int o = nbase + wc * 64 + j * 16 + l15;
            float bval = bp[o];
#pragma unroll
            for (int r = 0; r < 4; ++r)
                out[(size_t)(mrow + r) * CDIM + o] = acc[i][j][r] + bval;
        }
    }
}

// ---------------------------------------------------------------------------
// Output projection GEMM, fallback (r18-proven): reg staging, bf16 wpb.
// ---------------------------------------------------------------------------
__global__ __launch_bounds__(256) void gemm_p(
    const short* __restrict__ attn, const short* __restrict__ wpb,
    const float* __restrict__ bp, float* __restrict__ out) {
    __shared__ __attribute__((aligned(16))) short a_lds[64][40];
    __shared__ __attribute__((aligned(16))) short b_lds[128][40];

    const int tid = threadIdx.x;
    const int lane = tid & 63;
    const int wv = tid >> 6;
    const int wr = wv >> 1, wc = wv & 1;
    const int l15 = lane & 15, l4 = lane >> 4;
    const int mbase = blockIdx.x * 64;
    const int nbase = blockIdx.y * 128;

    f32x4 acc[2][4];
#pragma unroll
    for (int i = 0; i < 2; ++i)
#pragma unroll
        for (int j = 0; j < 4; ++j) acc[i][j] = f32x4{0.f, 0.f, 0.f, 0.f};

    const int arow = tid >> 2;
    const int acol = (tid & 3) * 8;
    const short* aptr = attn + (size_t)(mbase + arow) * CDIM + acol;
    const short* bptr = wpb + (size_t)(nbase + arow) * CDIM + acol;

    short8 apre, bpre[2];
    apre = *(const short8*)(aptr);
    bpre[0] = *(const short8*)(bptr);
    bpre[1] = *(const short8*)(bptr + (size_t)64 * CDIM);

    for (int k0 = 0; k0 < CDIM; k0 += 32) {
        __syncthreads();
        *(short8*)&a_lds[arow][acol] = apre;
        *(short8*)&b_lds[arow][acol] = bpre[0];
        *(short8*)&b_lds[arow + 64][acol] = bpre[1];
        __syncthreads();
        if (k0 + 32 < CDIM) {
            apre = *(const short8*)(aptr + k0 + 32);
            bpre[0] = *(const short8*)(bptr + k0 + 32);
            bpre[1] = *(const short8*)(bptr + (size_t)64 * CDIM + k0 + 32);
        }

        short8 af[2], bfr[4];
#pragma unroll
        for (int i = 0; i < 2; ++i)
            af[i] = *(const short8*)&a_lds[wr * 32 + i * 16 + l15][l4 * 8];
#pragma unroll
        for (int j = 0; j < 4; ++j)
            bfr[j] = *(const short8*)&b_lds[wc * 64 + j * 16 + l15][l4 * 8];
#pragma unroll
        for (int i = 0; i < 2; ++i)
#pragma unroll
            for (int j = 0; j < 4; ++j)
                acc[i][j] = mfma16(af[i], bfr[j], acc[i][j]);
    }

#pragma unroll
    for (int i = 0; i < 2; ++i) {
        int mrow = mbase + wr * 32 + i * 16 + l4 * 4;
#pragma unroll
        for (int j = 0; j < 4; ++j) {
            int o = nbase + wc * 64 + j * 16 + l15;
            float bval = bp[o];
#pragma unroll
            for (int r = 0; r < 4; ++r)
                out[(size_t)(mrow + r) * CDIM + o] = acc[i][j][r] + bval;
        }
    }
}

// ---------------------------------------------------------------------------
// Flash attention v9: v8 + per-wave diagonal-tile work skip. jt_lim =
// ceil((wrow0+16-kvbase)/16) is wave-uniform; columns >= kvbase+jt_lim*16
// are always causally masked, so their S-MFMAs/exps and the PV ks-slots
// covering only them are skipped (uniform branches; barriers untouched).
// ---------------------------------------------------------------------------
__global__ __launch_bounds__(256) void attn_kernel(
    const short* __restrict__ q, const short* __restrict__ k,
    const short* __restrict__ vt, short* __restrict__ attn_out) {
    __shared__ __attribute__((aligned(16))) short k_lds[128][64];
    __shared__ __attribute__((aligned(16))) short vt_lds[64][128];
    __shared__ __attribute__((aligned(16))) short p_lds[4][16][136];

    const int tid = threadIdx.x;
    const int w = tid >> 6;
    const int lane = tid & 63;
    const int l15 = lane & 15;
    const int l4 = lane >> 4;
    const int h = blockIdx.x;
    const int qtile = gridDim.y - 1 - blockIdx.y;
    const int wrow0 = qtile * 64 + w * 16;

    short8 qf[2];
#pragma unroll
    for (int kh = 0; kh < 2; ++kh)
        qf[kh] = *(const short8*)(q + ((size_t)h * TSEQ + wrow0 + l15) * DHEAD +
                                  kh * 32 + l4 * 8);

    const short onebf = (short)0x3F80;  // bf16(1.0)
    short8 vf_ones;
#pragma unroll
    for (int e = 0; e < 8; ++e) vf_ones[e] = (l15 == 0) ? onebf : (short)0;

    f32x4 o_acc[4];
    f32x4 o5 = f32x4{0.f, 0.f, 0.f, 0.f};
#pragma unroll
    for (int dt = 0; dt < 4; ++dt) o_acc[dt] = f32x4{0.f, 0.f, 0.f, 0.f};

    const int ntiles = (qtile + 2) >> 1;
    const size_t kbase = (size_t)h * TSEQ * DHEAD;
    const size_t vbase = (size_t)h * DHEAD * TSEQ;

    const int ksrow = tid >> 3, ksg = tid & 7;
    const int vsrow = tid >> 4, vsg = tid & 15;

    short8 kpre[4], vpre[4];
#pragma unroll
    for (int it = 0; it < 4; ++it) {
        kpre[it] = *(const short8*)(k + kbase + (size_t)(ksrow + it * 32) * DHEAD + ksg * 8);
        vpre[it] = *(const short8*)(vt + vbase + (size_t)(vsrow + it * 16) * TSEQ + vsg * 8);
    }

    for (int kvt = 0; kvt < ntiles; ++kvt) {
        const int kvbase = kvt * 128;
        __syncthreads();
#pragma unroll
        for (int it = 0; it < 4; ++it) {
            int krow = ksrow + it * 32;
            *(short8*)&k_lds[krow][(ksg ^ (krow & 7)) * 8] = kpre[it];
            int vrow = vsrow + it * 16;
            *(short8*)&vt_lds[vrow][((vsg ^ (vrow & 15))) * 8] = vpre[it];
        }
        __syncthreads();
        if (kvt + 1 < ntiles) {
            int kvb2 = kvbase + 128;
#pragma unroll
            for (int it = 0; it < 4; ++it) {
                kpre[it] = *(const short8*)(k + kbase + (size_t)(kvb2 + ksrow + it * 32) * DHEAD + ksg * 8);
                vpre[it] = *(const short8*)(vt + vbase + (size_t)(vsrow + it * 16) * TSEQ + kvb2 + vsg * 8);
            }
        }

        // wave-uniform useful-column bound for this tile
        const int over = wrow0 + 16 - kvbase;            // >= 16 always
        const int jt_lim = over >= 128 ? 8 : ((over + 15) >> 4);
        const int ks_lim = (jt_lim + 1) >> 1;
        const int zero_end = 2 * ks_lim;                 // zero-fill [jt_lim, zero_end)

        f32x4 s[8];
        __builtin_amdgcn_s_setprio(1);
#pragma unroll
        for (int jt = 0; jt < 8; ++jt) {
            if (jt < jt_lim) {
                int row = jt * 16 + l15;
                int sw = row & 7;
                short8 kf0 = *(const short8*)&k_lds[row][(l4 ^ sw) * 8];
                short8 kf1 = *(const short8*)&k_lds[row][((4 + l4) ^ sw) * 8];
                f32x4 a = f32x4{0.f, 0.f, 0.f, 0.f};
                a = mfma16(qf[0], kf0, a);
                a = mfma16(qf[1], kf1, a);
                s[jt] = a;
            }
        }
        __builtin_amdgcn_s_setprio(0);

        // softmax: p = native exp2(s); truncated bf16 store.
        if (kvbase + 127 > wrow0) {  // diagonal region: mask + jt_lim skip
#pragma unroll
            for (int r = 0; r < 4; ++r) {
                int qrow = wrow0 + l4 * 4 + r;
#pragma unroll
                for (int jt = 0; jt < 8; ++jt) {
                    if (jt < jt_lim) {
                        float x = s[jt][r];
                        if (kvbase + jt * 16 + l15 > qrow) x = -INFINITY;
                        unsigned int eb = __builtin_bit_cast(unsigned int,
                                                             __builtin_amdgcn_exp2f(x));
                        p_lds[w][l4 * 4 + r][jt * 16 + l15] = (short)(eb >> 16);
                    } else if (jt < zero_end) {
                        p_lds[w][l4 * 4 + r][jt * 16 + l15] = (short)0;
                    }
                }
            }
        } else {
#pragma unroll
            for (int r = 0; r < 4; ++r) {
#pragma unroll
                for (int jt = 0; jt < 8; ++jt) {
                    unsigned int eb = __builtin_bit_cast(unsigned int,
                                                         __builtin_amdgcn_exp2f(s[jt][r]));
                    p_lds[w][l4 * 4 + r][jt * 16 + l15] = (short)(eb >> 16);
                }
            }
        }

        short8 pa[4];
#pragma unroll
        for (int ks = 0; ks < 4; ++ks)
            if (ks < ks_lim)
                pa[ks] = *(const short8*)&p_lds[w][l15][ks * 32 + l4 * 8];
        __builtin_amdgcn_s_setprio(1);
#pragma unroll
        for (int dt = 0; dt < 4; ++dt) {
            int row = dt * 16 + l15;
            int sw = row & 15;
#pragma unroll
            for (int ks = 0; ks < 4; ++ks) {
                if (ks < ks_lim) {
                    short8 vf = *(const short8*)&vt_lds[row][((ks * 4 + l4) ^ sw) * 8];
                    o_acc[dt] = mfma16(pa[ks], vf, o_acc[dt]);
                }
            }
        }
#pragma unroll
        for (int ks = 0; ks < 4; ++ks)
            if (ks < ks_lim)
                o5 = mfma16(pa[ks], vf_ones, o5);
        __builtin_amdgcn_s_setprio(0);
    }

    float inv[4];
#pragma unroll
    for (int r = 0; r < 4; ++r)
        inv[r] = 1.0f / __shfl(o5[r], lane & 48);
    const int b = h >> 4, n = h & 15;
#pragma unroll
    for (int dt = 0; dt < 4; ++dt) {
#pragma unroll
        for (int r = 0; r < 4; ++r) {
            int t = wrow0 + l4 * 4 + r;
            attn_out[((size_t)b * TSEQ + t) * CDIM + n * DHEAD + dt * 16 + l15] =
                f2bf(o_acc[dt][r] * inv[r]);
        }
    }
}

extern "C" void kernel_launch(void* const* d_in, const int* in_sizes, int n_in,
                              void* d_out, int out_size, void* d_ws, size_t ws_size,
                              hipStream_t stream) {
    const float* x  = (const float*)d_in[0];
    const float* Wq = (const float*)d_in[1];
    const float* bq = (const float*)d_in[2];
    const float* Wk = (const float*)d_in[3];
    const float* bk = (const float*)d_in[4];
    const float* Wv = (const float*)d_in[5];
    const float* bv = (const float*)d_in[6];
    const float* Wp = (const float*)d_in[7];
    const float* bp = (const float*)d_in[8];

    char* ws = (char*)d_ws;
    const size_t SZ = (size_t)MROWS * CDIM * sizeof(short);  // 8 MB
    const size_t WSZ = (size_t)CDIM * CDIM * sizeof(short);  // 2 MB
    short* qws  = (short*)(ws);
    short* kws  = (short*)(ws + SZ);
    short* vtws = (short*)(ws + 2 * SZ);
    short* xb   = (short*)(ws + 3 * SZ);
    short* attn = xb;  // alias: xb dead after QKV GEMM

    if (ws_size >= 4 * SZ + 4 * WSZ) {
        short* wqb = (short*)(ws + 4 * SZ);
        short* wkb = wqb + (size_t)CDIM * CDIM;
        short* wvb = wkb + (size_t)CDIM * CDIM;
        short* wpb = wvb + (size_t)CDIM * CDIM;
        conv5_kernel<<<4096, 256, 0, stream>>>(x, Wq, Wk, Wv, Wp,
                                               xb, wqb, wkb, wvb, wpb);
        gemm_qkv_g<<<dim3(MROWS / 128, 24), 256, 0, stream>>>(
            xb, wqb, wkb, wvb, bq, bk, bv, qws, kws, vtws);
        attn_kernel<<<dim3(BSZ * NHEADS, TSEQ / 64), 256, 0, stream>>>(qws, kws, vtws, attn);
        gemm_p_g<<<dim3(MROWS / 64, CDIM / 128), 256, 0, stream>>>(attn, wpb, bp, (float*)d_out);
    } else {
        short* wpb = qws;  // alias: qws dead after attn
        convx_kernel<<<2048, 256, 0, stream>>>(x, xb);
        gemm_qkv<<<dim3(MROWS / 128, 24), 256, 0, stream>>>(
            xb, Wq, Wk, Wv, bq, bk, bv, qws, kws, vtws);
        attn_kernel<<<dim3(BSZ * NHEADS, TSEQ / 64), 256, 0, stream>>>(qws, kws, vtws, attn);
        convx_kernel<<<512, 256, 0, stream>>>(Wp, wpb);
        gemm_p<<<dim3(MROWS / 64, CDIM / 128), 256, 0, stream>>>(attn, wpb, bp, (float*)d_out);
    }
}

// Round 25
// 96.697 us; speedup vs baseline: 1.1760x; 1.1760x over previous
//
#include <hip/hip_runtime.h>
#include <hip/hip_bf16.h>
#include <math.h>

#define TSEQ 2048
#define CDIM 1024
#define NHEADS 16
#define DHEAD 64
#define BSZ 2
#define MROWS (BSZ * TSEQ)  // 4096
#define SCALE_Q 0.18033688f  // 0.125 * log2(e): softmax becomes exp2(s)

typedef __attribute__((ext_vector_type(8))) short short8;
typedef __attribute__((ext_vector_type(4))) short short4v;
typedef __attribute__((ext_vector_type(4))) float f32x4;

__device__ inline f32x4 mfma16(short8 a, short8 b, f32x4 c) {
    return __builtin_amdgcn_mfma_f32_16x16x32_bf16(a, b, c, 0, 0, 0);
}

__device__ inline short f2bf(float f) {
    __hip_bfloat16 h = __float2bfloat16(f);
    return __builtin_bit_cast(short, h);
}

__device__ inline void gl_lds16(const short* g, short* l) {
    __builtin_amdgcn_global_load_lds(
        (const __attribute__((address_space(1))) void*)g,
        (__attribute__((address_space(3))) void*)l, 16, 0, 0);
}

// ---------------------------------------------------------------------------
// conv f32 -> bf16, 8 elems/thread (x only; fallback path).
// ---------------------------------------------------------------------------
__global__ __launch_bounds__(256) void convx_kernel(const float* __restrict__ x,
                                                    short* __restrict__ xb) {
    size_t off = (size_t)(blockIdx.x * 256 + threadIdx.x) * 8;
    float4 a = *(const float4*)(x + off);
    float4 b = *(const float4*)(x + off + 4);
    short8 h;
    h[0] = f2bf(a.x); h[1] = f2bf(a.y); h[2] = f2bf(a.z); h[3] = f2bf(a.w);
    h[4] = f2bf(b.x); h[5] = f2bf(b.y); h[6] = f2bf(b.z); h[7] = f2bf(b.w);
    *(short8*)(xb + off) = h;
}

// conv x (4M) + Wq/Wk/Wv/Wp (1M each) -> bf16 in ONE launch (big-ws path).
__global__ __launch_bounds__(256) void conv5_kernel(
    const float* __restrict__ x, const float* __restrict__ swq,
    const float* __restrict__ swk, const float* __restrict__ swv,
    const float* __restrict__ swp, short* __restrict__ xb,
    short* __restrict__ wqb, short* __restrict__ wkb,
    short* __restrict__ wvb, short* __restrict__ wpb) {
    int chunk = blockIdx.x >> 9;               // 0..7 (512 blocks per 1M elems)
    size_t off = (size_t)((blockIdx.x & 511) * 256 + threadIdx.x) * 8;
    const float* s;
    short* d;
    if (chunk < 4)      { s = x + (size_t)chunk * 1048576; d = xb + (size_t)chunk * 1048576; }
    else if (chunk == 4){ s = swq; d = wqb; }
    else if (chunk == 5){ s = swk; d = wkb; }
    else if (chunk == 6){ s = swv; d = wvb; }
    else                { s = swp; d = wpb; }
    float4 a = *(const float4*)(s + off);
    float4 b = *(const float4*)(s + off + 4);
    short8 h;
    h[0] = f2bf(a.x); h[1] = f2bf(a.y); h[2] = f2bf(a.z); h[3] = f2bf(a.w);
    h[4] = f2bf(b.x); h[5] = f2bf(b.y); h[6] = f2bf(b.z); h[7] = f2bf(b.w);
    *(short8*)(d + off) = h;
}

// ---------------------------------------------------------------------------
// Fused QKV GEMM, gl_lds path (m97 structure, frozen).
// ---------------------------------------------------------------------------
__global__ __launch_bounds__(256, 3) void gemm_qkv_g(
    const short* __restrict__ xb, const short* __restrict__ wqb,
    const short* __restrict__ wkb, const short* __restrict__ wvb,
    const float* __restrict__ bq, const float* __restrict__ bk,
    const float* __restrict__ bv, short* __restrict__ qws,
    short* __restrict__ kws, short* __restrict__ vtws) {
    __shared__ __attribute__((aligned(16))) short a_lds[128 * 64];
    __shared__ __attribute__((aligned(16))) short b_lds[128 * 64];

    const int tid = threadIdx.x;
    const int lane = tid & 63;
    const int wv = tid >> 6;
    const int wr = wv >> 1, wc = wv & 1;
    const int l15 = lane & 15, l4 = lane >> 4;
    const int mbase = blockIdx.x * 128;
    const int which = blockIdx.y >> 3;
    const int nbase = (blockIdx.y & 7) * 128;
    const short* Wb = which == 0 ? wqb : (which == 1 ? wkb : wvb);
    const float* bias = which == 0 ? bq : (which == 1 ? bk : bv);

    f32x4 acc[4][4];
#pragma unroll
    for (int i = 0; i < 4; ++i)
#pragma unroll
        for (int j = 0; j < 4; ++j) acc[i][j] = f32x4{0.f, 0.f, 0.f, 0.f};

    const int srow = tid >> 3;
    const int gcol = (tid & 7) ^ (srow & 7);
    const short* asrc = xb + (size_t)(mbase + srow) * CDIM + gcol * 8;
    const short* bsrc = Wb + (size_t)(nbase + srow) * CDIM + gcol * 8;
    short* adst = &a_lds[tid * 8];
    short* bdst = &b_lds[tid * 8];

    for (int k0 = 0; k0 < CDIM; k0 += 64) {
        __syncthreads();
#pragma unroll
        for (int it = 0; it < 4; ++it) {
            gl_lds16(asrc + (size_t)(it * 32) * CDIM + k0, adst + it * 2048);
            gl_lds16(bsrc + (size_t)(it * 32) * CDIM + k0, bdst + it * 2048);
        }
        __syncthreads();

#pragma unroll
        for (int kk = 0; kk < 2; ++kk) {
            short8 af[4], bfr[4];
#pragma unroll
            for (int i = 0; i < 4; ++i) {
                int R = wr * 64 + i * 16 + l15;
                af[i] = *(const short8*)&a_lds[R * 64 + ((kk * 4 + l4) ^ (R & 7)) * 8];
            }
#pragma unroll
            for (int j = 0; j < 4; ++j) {
                int R = wc * 64 + j * 16 + l15;
                bfr[j] = *(const short8*)&b_lds[R * 64 + ((kk * 4 + l4) ^ (R & 7)) * 8];
            }
#pragma unroll
            for (int i = 0; i < 4; ++i)
#pragma unroll
                for (int j = 0; j < 4; ++j)
                    acc[i][j] = mfma16(af[i], bfr[j], acc[i][j]);
        }
    }

    if (which < 2) {
        short* dst = which == 0 ? qws : kws;
        const float scale = which == 0 ? SCALE_Q : 1.0f;
#pragma unroll
        for (int i = 0; i < 4; ++i) {
            int mrow = mbase + wr * 64 + i * 16 + l4 * 4;
#pragma unroll
            for (int j = 0; j < 4; ++j) {
                int o = nbase + wc * 64 + j * 16 + l15;
                int n = o >> 6, d = o & 63;
                float bval = bias[o];
#pragma unroll
                for (int r = 0; r < 4; ++r) {
                    int mm = mrow + r;
                    int bb = mm >> 11;
                    int t = mm & (TSEQ - 1);
                    dst[(((size_t)bb * NHEADS + n) * TSEQ + t) * DHEAD + d] =
                        f2bf((acc[i][j][r] + bval) * scale);
                }
            }
        }
    } else {
#pragma unroll
        for (int i = 0; i < 4; ++i) {
            int mrow = mbase + wr * 64 + i * 16 + l4 * 4;
            int bb = mrow >> 11;
            int t = mrow & (TSEQ - 1);
#pragma unroll
            for (int j = 0; j < 4; ++j) {
                int o = nbase + wc * 64 + j * 16 + l15;
                int n = o >> 6, d = o & 63;
                float bval = bias[o];
                short4v h4;
#pragma unroll
                for (int r = 0; r < 4; ++r) h4[r] = f2bf(acc[i][j][r] + bval);
                *(short4v*)&vtws[(((size_t)bb * NHEADS + n) * DHEAD + d) * TSEQ + t] = h4;
            }
        }
    }
}

// ---------------------------------------------------------------------------
// Fused QKV GEMM, fallback path (r18-proven): f32 weights, reg staging.
// ---------------------------------------------------------------------------
__global__ __launch_bounds__(256, 3) void gemm_qkv(
    const short* __restrict__ xb, const float* __restrict__ Wq,
    const float* __restrict__ Wk, const float* __restrict__ Wv,
    const float* __restrict__ bq, const float* __restrict__ bk,
    const float* __restrict__ bv, short* __restrict__ qws,
    short* __restrict__ kws, short* __restrict__ vtws) {
    __shared__ __attribute__((aligned(16))) short a_lds[128][72];
    __shared__ __attribute__((aligned(16))) short b_lds[128][72];

    const int tid = threadIdx.x;
    const int lane = tid & 63;
    const int wv = tid >> 6;
    const int wr = wv >> 1, wc = wv & 1;
    const int l15 = lane & 15, l4 = lane >> 4;
    const int mbase = blockIdx.x * 128;
    const int which = blockIdx.y >> 3;
    const int nbase = (blockIdx.y & 7) * 128;
    const float* Wf = which == 0 ? Wq : (which == 1 ? Wk : Wv);
    const float* bias = which == 0 ? bq : (which == 1 ? bk : bv);

    f32x4 acc[4][4];
#pragma unroll
    for (int i = 0; i < 4; ++i)
#pragma unroll
        for (int j = 0; j < 4; ++j) acc[i][j] = f32x4{0.f, 0.f, 0.f, 0.f};

    const int ar = tid >> 3;
    const int ag = (tid & 7) * 8;
    const int br = tid >> 4;
    const int bg = (tid & 15) * 4;
    const short* aptr = xb + (size_t)(mbase + ar) * CDIM + ag;
    const float* bptr = Wf + (size_t)(nbase + br) * CDIM + bg;

    short8 apre[4];
    float4 bpre[8];
#pragma unroll
    for (int it = 0; it < 4; ++it)
        apre[it] = *(const short8*)(aptr + (size_t)(32 * it) * CDIM);
#pragma unroll
    for (int it = 0; it < 8; ++it)
        bpre[it] = *(const float4*)(bptr + (size_t)(16 * it) * CDIM);

    for (int k0 = 0; k0 < CDIM; k0 += 64) {
        __syncthreads();
#pragma unroll
        for (int it = 0; it < 4; ++it)
            *(short8*)&a_lds[ar + 32 * it][ag] = apre[it];
#pragma unroll
        for (int it = 0; it < 8; ++it) {
            short4v h;
            h.x = f2bf(bpre[it].x); h.y = f2bf(bpre[it].y);
            h.z = f2bf(bpre[it].z); h.w = f2bf(bpre[it].w);
            *(short4v*)&b_lds[br + 16 * it][bg] = h;
        }
        __syncthreads();
        if (k0 + 64 < CDIM) {
#pragma unroll
            for (int it = 0; it < 4; ++it)
                apre[it] = *(const short8*)(aptr + (size_t)(32 * it) * CDIM + k0 + 64);
#pragma unroll
            for (int it = 0; it < 8; ++it)
                bpre[it] = *(const float4*)(bptr + (size_t)(16 * it) * CDIM + k0 + 64);
        }

#pragma unroll
        for (int kk = 0; kk < 2; ++kk) {
            short8 af[4], bfr[4];
#pragma unroll
            for (int i = 0; i < 4; ++i)
                af[i] = *(const short8*)&a_lds[wr * 64 + i * 16 + l15][kk * 32 + l4 * 8];
#pragma unroll
            for (int j = 0; j < 4; ++j)
                bfr[j] = *(const short8*)&b_lds[wc * 64 + j * 16 + l15][kk * 32 + l4 * 8];
#pragma unroll
            for (int i = 0; i < 4; ++i)
#pragma unroll
                for (int j = 0; j < 4; ++j)
                    acc[i][j] = mfma16(af[i], bfr[j], acc[i][j]);
        }
    }

    if (which < 2) {
        short* dst = which == 0 ? qws : kws;
        const float scale = which == 0 ? SCALE_Q : 1.0f;
#pragma unroll
        for (int i = 0; i < 4; ++i) {
            int mrow = mbase + wr * 64 + i * 16 + l4 * 4;
#pragma unroll
            for (int j = 0; j < 4; ++j) {
                int o = nbase + wc * 64 + j * 16 + l15;
                int n = o >> 6, d = o & 63;
                float bval = bias[o];
#pragma unroll
                for (int r = 0; r < 4; ++r) {
                    int mm = mrow + r;
                    int bb = mm >> 11;
                    int t = mm & (TSEQ - 1);
                    dst[(((size_t)bb * NHEADS + n) * TSEQ + t) * DHEAD + d] =
                        f2bf((acc[i][j][r] + bval) * scale);
                }
            }
        }
    } else {
#pragma unroll
        for (int i = 0; i < 4; ++i) {
            int mrow = mbase + wr * 64 + i * 16 + l4 * 4;
            int bb = mrow >> 11;
            int t = mrow & (TSEQ - 1);
#pragma unroll
            for (int j = 0; j < 4; ++j) {
                int o = nbase + wc * 64 + j * 16 + l15;
                int n = o >> 6, d = o & 63;
                float bval = bias[o];
                short4v h4;
#pragma unroll
                for (int r = 0; r < 4; ++r) h4[r] = f2bf(acc[i][j][r] + bval);
                *(short4v*)&vtws[(((size_t)bb * NHEADS + n) * DHEAD + d) * TSEQ + t] = h4;
            }
        }
    }
}

// ---------------------------------------------------------------------------
// Output projection GEMM, gl_lds path (frozen from r22).
// ---------------------------------------------------------------------------
__global__ __launch_bounds__(256) void gemm_p_g(
    const short* __restrict__ attn, const short* __restrict__ wpb,
    const float* __restrict__ bp, float* __restrict__ out) {
    __shared__ __attribute__((aligned(16))) short a_lds[64 * 64];
    __shared__ __attribute__((aligned(16))) short b_lds[128 * 64];

    const int tid = threadIdx.x;
    const int lane = tid & 63;
    const int wv = tid >> 6;
    const int wr = wv >> 1, wc = wv & 1;
    const int l15 = lane & 15, l4 = lane >> 4;
    const int mbase = blockIdx.x * 64;
    const int nbase = blockIdx.y * 128;

    f32x4 acc[2][4];
#pragma unroll
    for (int i = 0; i < 2; ++i)
#pragma unroll
        for (int j = 0; j < 4; ++j) acc[i][j] = f32x4{0.f, 0.f, 0.f, 0.f};

    const int srow = tid >> 3;
    const int gcol = (tid & 7) ^ (srow & 7);
    const short* asrc = attn + (size_t)(mbase + srow) * CDIM + gcol * 8;
    const short* bsrc = wpb + (size_t)(nbase + srow) * CDIM + gcol * 8;
    short* adst = &a_lds[tid * 8];
    short* bdst = &b_lds[tid * 8];

    for (int k0 = 0; k0 < CDIM; k0 += 64) {
        __syncthreads();
#pragma unroll
        for (int it = 0; it < 2; ++it)
            gl_lds16(asrc + (size_t)(it * 32) * CDIM + k0, adst + it * 2048);
#pragma unroll
        for (int it = 0; it < 4; ++it)
            gl_lds16(bsrc + (size_t)(it * 32) * CDIM + k0, bdst + it * 2048);
        __syncthreads();

#pragma unroll
        for (int kk = 0; kk < 2; ++kk) {
            short8 af[2], bfr[4];
#pragma unroll
            for (int i = 0; i < 2; ++i) {
                int R = wr * 32 + i * 16 + l15;
                af[i] = *(const short8*)&a_lds[R * 64 + ((kk * 4 + l4) ^ (R & 7)) * 8];
            }
#pragma unroll
            for (int j = 0; j < 4; ++j) {
                int R = wc * 64 + j * 16 + l15;
                bfr[j] = *(const short8*)&b_lds[R * 64 + ((kk * 4 + l4) ^ (R & 7)) * 8];
            }
#pragma unroll
            for (int i = 0; i < 2; ++i)
#pragma unroll
                for (int j = 0; j < 4; ++j)
                    acc[i][j] = mfma16(af[i], bfr[j], acc[i][j]);
        }
    }

#pragma unroll
    for (int i = 0; i < 2; ++i) {
        int mrow = mbase + wr * 32 + i * 16 + l4 * 4;
#pragma unroll
        for (int j = 0; j < 4; ++j) {
            int o = nbase + wc * 64 + j * 16 + l15;
            float bval = bp[o];
#pragma unroll
            for (int r = 0; r < 4; ++r)
                out[(size_t)(mrow + r) * CDIM + o] = acc[i][j][r] + bval;
        }
    }
}

// ---------------------------------------------------------------------------
// Output projection GEMM, fallback (r18-proven): reg staging, bf16 wpb.
// ---------------------------------------------------------------------------
__global__ __launch_bounds__(256) void gemm_p(
    const short* __restrict__ attn, const short* __restrict__ wpb,
    const float* __restrict__ bp, float* __restrict__ out) {
    __shared__ __attribute__((aligned(16))) short a_lds[64][40];
    __shared__ __attribute__((aligned(16))) short b_lds[128][40];

    const int tid = threadIdx.x;
    const int lane = tid & 63;
    const int wv = tid >> 6;
    const int wr = wv >> 1, wc = wv & 1;
    const int l15 = lane & 15, l4 = lane >> 4;
    const int mbase = blockIdx.x * 64;
    const int nbase = blockIdx.y * 128;

    f32x4 acc[2][4];
#pragma unroll
    for (int i = 0; i < 2; ++i)
#pragma unroll
        for (int j = 0; j < 4; ++j) acc[i][j] = f32x4{0.f, 0.f, 0.f, 0.f};

    const int arow = tid >> 2;
    const int acol = (tid & 3) * 8;
    const short* aptr = attn + (size_t)(mbase + arow) * CDIM + acol;
    const short* bptr = wpb + (size_t)(nbase + arow) * CDIM + acol;

    short8 apre, bpre[2];
    apre = *(const short8*)(aptr);
    bpre[0] = *(const short8*)(bptr);
    bpre[1] = *(const short8*)(bptr + (size_t)64 * CDIM);

    for (int k0 = 0; k0 < CDIM; k0 += 32) {
        __syncthreads();
        *(short8*)&a_lds[arow][acol] = apre;
        *(short8*)&b_lds[arow][acol] = bpre[0];
        *(short8*)&b_lds[arow + 64][acol] = bpre[1];
        __syncthreads();
        if (k0 + 32 < CDIM) {
            apre = *(const short8*)(aptr + k0 + 32);
            bpre[0] = *(const short8*)(bptr + k0 + 32);
            bpre[1] = *(const short8*)(bptr + (size_t)64 * CDIM + k0 + 32);
        }

        short8 af[2], bfr[4];
#pragma unroll
        for (int i = 0; i < 2; ++i)
            af[i] = *(const short8*)&a_lds[wr * 32 + i * 16 + l15][l4 * 8];
#pragma unroll
        for (int j = 0; j < 4; ++j)
            bfr[j] = *(const short8*)&b_lds[wc * 64 + j * 16 + l15][l4 * 8];
#pragma unroll
        for (int i = 0; i < 2; ++i)
#pragma unroll
            for (int j = 0; j < 4; ++j)
                acc[i][j] = mfma16(af[i], bfr[j], acc[i][j]);
    }

#pragma unroll
    for (int i = 0; i < 2; ++i) {
        int mrow = mbase + wr * 32 + i * 16 + l4 * 4;
#pragma unroll
        for (int j = 0; j < 4; ++j) {
            int o = nbase + wc * 64 + j * 16 + l15;
            float bval = bp[o];
#pragma unroll
            for (int r = 0; r < 4; ++r)
                out[(size_t)(mrow + r) * CDIM + o] = acc[i][j][r] + bval;
        }
    }
}

// ---------------------------------------------------------------------------
// Flash attention v8 (r23-passing, reverted): QBLK=64 (4 waves x 16 q-rows),
// KVBLK=128, no-max softmax via native exp2 (q pre-scaled), l via ones-row
// MFMA, truncated bf16 P, setprio around MFMA clusters, hoisted wave-uniform
// causal-mask branch, K/V reg-prefetch into XOR-swizzled LDS.
// ---------------------------------------------------------------------------
__global__ __launch_bounds__(256) void attn_kernel(
    const short* __restrict__ q, const short* __restrict__ k,
    const short* __restrict__ vt, short* __restrict__ attn_out) {
    __shared__ __attribute__((aligned(16))) short k_lds[128][64];
    __shared__ __attribute__((aligned(16))) short vt_lds[64][128];
    __shared__ __attribute__((aligned(16))) short p_lds[4][16][136];

    const int tid = threadIdx.x;
    const int w = tid >> 6;
    const int lane = tid & 63;
    const int l15 = lane & 15;
    const int l4 = lane >> 4;
    const int h = blockIdx.x;
    const int qtile = gridDim.y - 1 - blockIdx.y;
    const int wrow0 = qtile * 64 + w * 16;

    short8 qf[2];
#pragma unroll
    for (int kh = 0; kh < 2; ++kh)
        qf[kh] = *(const short8*)(q + ((size_t)h * TSEQ + wrow0 + l15) * DHEAD +
                                  kh * 32 + l4 * 8);

    const short onebf = (short)0x3F80;  // bf16(1.0)
    short8 vf_ones;
#pragma unroll
    for (int e = 0; e < 8; ++e) vf_ones[e] = (l15 == 0) ? onebf : (short)0;

    f32x4 o_acc[4];
    f32x4 o5 = f32x4{0.f, 0.f, 0.f, 0.f};
#pragma unroll
    for (int dt = 0; dt < 4; ++dt) o_acc[dt] = f32x4{0.f, 0.f, 0.f, 0.f};

    const int ntiles = (qtile + 2) >> 1;
    const size_t kbase = (size_t)h * TSEQ * DHEAD;
    const size_t vbase = (size_t)h * DHEAD * TSEQ;

    const int ksrow = tid >> 3, ksg = tid & 7;
    const int vsrow = tid >> 4, vsg = tid & 15;

    short8 kpre[4], vpre[4];
#pragma unroll
    for (int it = 0; it < 4; ++it) {
        kpre[it] = *(const short8*)(k + kbase + (size_t)(ksrow + it * 32) * DHEAD + ksg * 8);
        vpre[it] = *(const short8*)(vt + vbase + (size_t)(vsrow + it * 16) * TSEQ + vsg * 8);
    }

    for (int kvt = 0; kvt < ntiles; ++kvt) {
        const int kvbase = kvt * 128;
        __syncthreads();
#pragma unroll
        for (int it = 0; it < 4; ++it) {
            int krow = ksrow + it * 32;
            *(short8*)&k_lds[krow][(ksg ^ (krow & 7)) * 8] = kpre[it];
            int vrow = vsrow + it * 16;
            *(short8*)&vt_lds[vrow][((vsg ^ (vrow & 15))) * 8] = vpre[it];
        }
        __syncthreads();
        if (kvt + 1 < ntiles) {
            int kvb2 = kvbase + 128;
#pragma unroll
            for (int it = 0; it < 4; ++it) {
                kpre[it] = *(const short8*)(k + kbase + (size_t)(kvb2 + ksrow + it * 32) * DHEAD + ksg * 8);
                vpre[it] = *(const short8*)(vt + vbase + (size_t)(vsrow + it * 16) * TSEQ + kvb2 + vsg * 8);
            }
        }

        f32x4 s[8];
        __builtin_amdgcn_s_setprio(1);
#pragma unroll
        for (int jt = 0; jt < 8; ++jt) {
            int row = jt * 16 + l15;
            int sw = row & 7;
            short8 kf0 = *(const short8*)&k_lds[row][(l4 ^ sw) * 8];
            short8 kf1 = *(const short8*)&k_lds[row][((4 + l4) ^ sw) * 8];
            f32x4 a = f32x4{0.f, 0.f, 0.f, 0.f};
            a = mfma16(qf[0], kf0, a);
            a = mfma16(qf[1], kf1, a);
            s[jt] = a;
        }
        __builtin_amdgcn_s_setprio(0);

        // softmax: p = native exp2(s); truncated bf16 store.
        // Wave-uniform mask branch: only the diagonal tile pays mask cost.
        if (kvbase + 127 > wrow0) {
#pragma unroll
            for (int r = 0; r < 4; ++r) {
                int qrow = wrow0 + l4 * 4 + r;
#pragma unroll
                for (int jt = 0; jt < 8; ++jt) {
                    float x = s[jt][r];
                    if (kvbase + jt * 16 + l15 > qrow) x = -INFINITY;
                    unsigned int eb = __builtin_bit_cast(unsigned int,
                                                         __builtin_amdgcn_exp2f(x));
                    p_lds[w][l4 * 4 + r][jt * 16 + l15] = (short)(eb >> 16);
                }
            }
        } else {
#pragma unroll
            for (int r = 0; r < 4; ++r) {
#pragma unroll
                for (int jt = 0; jt < 8; ++jt) {
                    unsigned int eb = __builtin_bit_cast(unsigned int,
                                                         __builtin_amdgcn_exp2f(s[jt][r]));
                    p_lds[w][l4 * 4 + r][jt * 16 + l15] = (short)(eb >> 16);
                }
            }
        }

        short8 pa[4];
#pragma unroll
        for (int ks = 0; ks < 4; ++ks)
            pa[ks] = *(const short8*)&p_lds[w][l15][ks * 32 + l4 * 8];
        __builtin_amdgcn_s_setprio(1);
#pragma unroll
        for (int dt = 0; dt < 4; ++dt) {
            int row = dt * 16 + l15;
            int sw = row & 15;
#pragma unroll
            for (int ks = 0; ks < 4; ++ks) {
                short8 vf = *(const short8*)&vt_lds[row][((ks * 4 + l4) ^ sw) * 8];
                o_acc[dt] = mfma16(pa[ks], vf, o_acc[dt]);
            }
        }
#pragma unroll
        for (int ks = 0; ks < 4; ++ks)
            o5 = mfma16(pa[ks], vf_ones, o5);
        __builtin_amdgcn_s_setprio(0);
    }

    float inv[4];
#pragma unroll
    for (int r = 0; r < 4; ++r)
        inv[r] = 1.0f / __shfl(o5[r], lane & 48);
    const int b = h >> 4, n = h & 15;
#pragma unroll
    for (int dt = 0; dt < 4; ++dt) {
#pragma unroll
        for (int r = 0; r < 4; ++r) {
            int t = wrow0 + l4 * 4 + r;
            attn_out[((size_t)b * TSEQ + t) * CDIM + n * DHEAD + dt * 16 + l15] =
                f2bf(o_acc[dt][r] * inv[r]);
        }
    }
}

extern "C" void kernel_launch(void* const* d_in, const int* in_sizes, int n_in,
                              void* d_out, int out_size, void* d_ws, size_t ws_size,
                              hipStream_t stream) {
    const float* x  = (const float*)d_in[0];
    const float* Wq = (const float*)d_in[1];
    const float* bq = (const float*)d_in[2];
    const float* Wk = (const float*)d_in[3];
    const float* bk = (const float*)d_in[4];
    const float* Wv = (const float*)d_in[5];
    const float* bv = (const float*)d_in[6];
    const float* Wp = (const float*)d_in[7];
    const float* bp = (const float*)d_in[8];

    char* ws = (char*)d_ws;
    const size_t SZ = (size_t)MROWS * CDIM * sizeof(short);  // 8 MB
    const size_t WSZ = (size_t)CDIM * CDIM * sizeof(short);  // 2 MB
    short* qws  = (short*)(ws);
    short* kws  = (short*)(ws + SZ);
    short* vtws = (short*)(ws + 2 * SZ);
    short* xb   = (short*)(ws + 3 * SZ);
    short* attn = xb;  // alias: xb dead after QKV GEMM

    if (ws_size >= 4 * SZ + 4 * WSZ) {
        short* wqb = (short*)(ws + 4 * SZ);
        short* wkb = wqb + (size_t)CDIM * CDIM;
        short* wvb = wkb + (size_t)CDIM * CDIM;
        short* wpb = wvb + (size_t)CDIM * CDIM;
        conv5_kernel<<<4096, 256, 0, stream>>>(x, Wq, Wk, Wv, Wp,
                                               xb, wqb, wkb, wvb, wpb);
        gemm_qkv_g<<<dim3(MROWS / 128, 24), 256, 0, stream>>>(
            xb, wqb, wkb, wvb, bq, bk, bv, qws, kws, vtws);
        attn_kernel<<<dim3(BSZ * NHEADS, TSEQ / 64), 256, 0, stream>>>(qws, kws, vtws, attn);
        gemm_p_g<<<dim3(MROWS / 64, CDIM / 128), 256, 0, stream>>>(attn, wpb, bp, (float*)d_out);
    } else {
        short* wpb = qws;  // alias: qws dead after attn
        convx_kernel<<<2048, 256, 0, stream>>>(x, xb);
        gemm_qkv<<<dim3(MROWS / 128, 24), 256, 0, stream>>>(
            xb, Wq, Wk, Wv, bq, bk, bv, qws, kws, vtws);
        attn_kernel<<<dim3(BSZ * NHEADS, TSEQ / 64), 256, 0, stream>>>(qws, kws, vtws, attn);
        convx_kernel<<<512, 256, 0, stream>>>(Wp, wpb);
        gemm_p<<<dim3(MROWS / 64, CDIM / 128), 256, 0, stream>>>(attn, wpb, bp, (float*)d_out);
    }
}

// Round 26
// 96.407 us; speedup vs baseline: 1.1795x; 1.0030x over previous
//
#include <hip/hip_runtime.h>
#include <hip/hip_bf16.h>
#include <math.h>

#define TSEQ 2048
#define CDIM 1024
#define NHEADS 16
#define DHEAD 64
#define BSZ 2
#define MROWS (BSZ * TSEQ)  // 4096
#define SCALE_Q 0.18033688f  // 0.125 * log2(e): softmax becomes exp2(s)

typedef __attribute__((ext_vector_type(8))) short short8;
typedef __attribute__((ext_vector_type(4))) short short4v;
typedef __attribute__((ext_vector_type(4))) float f32x4;

__device__ inline f32x4 mfma16(short8 a, short8 b, f32x4 c) {
    return __builtin_amdgcn_mfma_f32_16x16x32_bf16(a, b, c, 0, 0, 0);
}

__device__ inline short f2bf(float f) {
    __hip_bfloat16 h = __float2bfloat16(f);
    return __builtin_bit_cast(short, h);
}

__device__ inline void gl_lds16(const short* g, short* l) {
    __builtin_amdgcn_global_load_lds(
        (const __attribute__((address_space(1))) void*)g,
        (__attribute__((address_space(3))) void*)l, 16, 0, 0);
}

// ---------------------------------------------------------------------------
// conv f32 -> bf16, 8 elems/thread (x only; fallback path).
// ---------------------------------------------------------------------------
__global__ __launch_bounds__(256) void convx_kernel(const float* __restrict__ x,
                                                    short* __restrict__ xb) {
    size_t off = (size_t)(blockIdx.x * 256 + threadIdx.x) * 8;
    float4 a = *(const float4*)(x + off);
    float4 b = *(const float4*)(x + off + 4);
    short8 h;
    h[0] = f2bf(a.x); h[1] = f2bf(a.y); h[2] = f2bf(a.z); h[3] = f2bf(a.w);
    h[4] = f2bf(b.x); h[5] = f2bf(b.y); h[6] = f2bf(b.z); h[7] = f2bf(b.w);
    *(short8*)(xb + off) = h;
}

// conv x (4M) + Wq/Wk/Wv/Wp (1M each) -> bf16 in ONE launch (big-ws path).
__global__ __launch_bounds__(256) void conv5_kernel(
    const float* __restrict__ x, const float* __restrict__ swq,
    const float* __restrict__ swk, const float* __restrict__ swv,
    const float* __restrict__ swp, short* __restrict__ xb,
    short* __restrict__ wqb, short* __restrict__ wkb,
    short* __restrict__ wvb, short* __restrict__ wpb) {
    int chunk = blockIdx.x >> 9;               // 0..7 (512 blocks per 1M elems)
    size_t off = (size_t)((blockIdx.x & 511) * 256 + threadIdx.x) * 8;
    const float* s;
    short* d;
    if (chunk < 4)      { s = x + (size_t)chunk * 1048576; d = xb + (size_t)chunk * 1048576; }
    else if (chunk == 4){ s = swq; d = wqb; }
    else if (chunk == 5){ s = swk; d = wkb; }
    else if (chunk == 6){ s = swv; d = wvb; }
    else                { s = swp; d = wpb; }
    float4 a = *(const float4*)(s + off);
    float4 b = *(const float4*)(s + off + 4);
    short8 h;
    h[0] = f2bf(a.x); h[1] = f2bf(a.y); h[2] = f2bf(a.z); h[3] = f2bf(a.w);
    h[4] = f2bf(b.x); h[5] = f2bf(b.y); h[6] = f2bf(b.z); h[7] = f2bf(b.w);
    *(short8*)(d + off) = h;
}

// ---------------------------------------------------------------------------
// Fused QKV GEMM, gl_lds path (m97 structure, frozen).
// ---------------------------------------------------------------------------
__global__ __launch_bounds__(256, 3) void gemm_qkv_g(
    const short* __restrict__ xb, const short* __restrict__ wqb,
    const short* __restrict__ wkb, const short* __restrict__ wvb,
    const float* __restrict__ bq, const float* __restrict__ bk,
    const float* __restrict__ bv, short* __restrict__ qws,
    short* __restrict__ kws, short* __restrict__ vtws) {
    __shared__ __attribute__((aligned(16))) short a_lds[128 * 64];
    __shared__ __attribute__((aligned(16))) short b_lds[128 * 64];

    const int tid = threadIdx.x;
    const int lane = tid & 63;
    const int wv = tid >> 6;
    const int wr = wv >> 1, wc = wv & 1;
    const int l15 = lane & 15, l4 = lane >> 4;
    const int mbase = blockIdx.x * 128;
    const int which = blockIdx.y >> 3;
    const int nbase = (blockIdx.y & 7) * 128;
    const short* Wb = which == 0 ? wqb : (which == 1 ? wkb : wvb);
    const float* bias = which == 0 ? bq : (which == 1 ? bk : bv);

    f32x4 acc[4][4];
#pragma unroll
    for (int i = 0; i < 4; ++i)
#pragma unroll
        for (int j = 0; j < 4; ++j) acc[i][j] = f32x4{0.f, 0.f, 0.f, 0.f};

    const int srow = tid >> 3;
    const int gcol = (tid & 7) ^ (srow & 7);
    const short* asrc = xb + (size_t)(mbase + srow) * CDIM + gcol * 8;
    const short* bsrc = Wb + (size_t)(nbase + srow) * CDIM + gcol * 8;
    short* adst = &a_lds[tid * 8];
    short* bdst = &b_lds[tid * 8];

    for (int k0 = 0; k0 < CDIM; k0 += 64) {
        __syncthreads();
#pragma unroll
        for (int it = 0; it < 4; ++it) {
            gl_lds16(asrc + (size_t)(it * 32) * CDIM + k0, adst + it * 2048);
            gl_lds16(bsrc + (size_t)(it * 32) * CDIM + k0, bdst + it * 2048);
        }
        __syncthreads();

#pragma unroll
        for (int kk = 0; kk < 2; ++kk) {
            short8 af[4], bfr[4];
#pragma unroll
            for (int i = 0; i < 4; ++i) {
                int R = wr * 64 + i * 16 + l15;
                af[i] = *(const short8*)&a_lds[R * 64 + ((kk * 4 + l4) ^ (R & 7)) * 8];
            }
#pragma unroll
            for (int j = 0; j < 4; ++j) {
                int R = wc * 64 + j * 16 + l15;
                bfr[j] = *(const short8*)&b_lds[R * 64 + ((kk * 4 + l4) ^ (R & 7)) * 8];
            }
#pragma unroll
            for (int i = 0; i < 4; ++i)
#pragma unroll
                for (int j = 0; j < 4; ++j)
                    acc[i][j] = mfma16(af[i], bfr[j], acc[i][j]);
        }
    }

    if (which < 2) {
        short* dst = which == 0 ? qws : kws;
        const float scale = which == 0 ? SCALE_Q : 1.0f;
#pragma unroll
        for (int i = 0; i < 4; ++i) {
            int mrow = mbase + wr * 64 + i * 16 + l4 * 4;
#pragma unroll
            for (int j = 0; j < 4; ++j) {
                int o = nbase + wc * 64 + j * 16 + l15;
                int n = o >> 6, d = o & 63;
                float bval = bias[o];
#pragma unroll
                for (int r = 0; r < 4; ++r) {
                    int mm = mrow + r;
                    int bb = mm >> 11;
                    int t = mm & (TSEQ - 1);
                    dst[(((size_t)bb * NHEADS + n) * TSEQ + t) * DHEAD + d] =
                        f2bf((acc[i][j][r] + bval) * scale);
                }
            }
        }
    } else {
#pragma unroll
        for (int i = 0; i < 4; ++i) {
            int mrow = mbase + wr * 64 + i * 16 + l4 * 4;
            int bb = mrow >> 11;
            int t = mrow & (TSEQ - 1);
#pragma unroll
            for (int j = 0; j < 4; ++j) {
                int o = nbase + wc * 64 + j * 16 + l15;
                int n = o >> 6, d = o & 63;
                float bval = bias[o];
                short4v h4;
#pragma unroll
                for (int r = 0; r < 4; ++r) h4[r] = f2bf(acc[i][j][r] + bval);
                *(short4v*)&vtws[(((size_t)bb * NHEADS + n) * DHEAD + d) * TSEQ + t] = h4;
            }
        }
    }
}

// ---------------------------------------------------------------------------
// Fused QKV GEMM, fallback path (r18-proven): f32 weights, reg staging.
// ---------------------------------------------------------------------------
__global__ __launch_bounds__(256, 3) void gemm_qkv(
    const short* __restrict__ xb, const float* __restrict__ Wq,
    const float* __restrict__ Wk, const float* __restrict__ Wv,
    const float* __restrict__ bq, const float* __restrict__ bk,
    const float* __restrict__ bv, short* __restrict__ qws,
    short* __restrict__ kws, short* __restrict__ vtws) {
    __shared__ __attribute__((aligned(16))) short a_lds[128][72];
    __shared__ __attribute__((aligned(16))) short b_lds[128][72];

    const int tid = threadIdx.x;
    const int lane = tid & 63;
    const int wv = tid >> 6;
    const int wr = wv >> 1, wc = wv & 1;
    const int l15 = lane & 15, l4 = lane >> 4;
    const int mbase = blockIdx.x * 128;
    const int which = blockIdx.y >> 3;
    const int nbase = (blockIdx.y & 7) * 128;
    const float* Wf = which == 0 ? Wq : (which == 1 ? Wk : Wv);
    const float* bias = which == 0 ? bq : (which == 1 ? bk : bv);

    f32x4 acc[4][4];
#pragma unroll
    for (int i = 0; i < 4; ++i)
#pragma unroll
        for (int j = 0; j < 4; ++j) acc[i][j] = f32x4{0.f, 0.f, 0.f, 0.f};

    const int ar = tid >> 3;
    const int ag = (tid & 7) * 8;
    const int br = tid >> 4;
    const int bg = (tid & 15) * 4;
    const short* aptr = xb + (size_t)(mbase + ar) * CDIM + ag;
    const float* bptr = Wf + (size_t)(nbase + br) * CDIM + bg;

    short8 apre[4];
    float4 bpre[8];
#pragma unroll
    for (int it = 0; it < 4; ++it)
        apre[it] = *(const short8*)(aptr + (size_t)(32 * it) * CDIM);
#pragma unroll
    for (int it = 0; it < 8; ++it)
        bpre[it] = *(const float4*)(bptr + (size_t)(16 * it) * CDIM);

    for (int k0 = 0; k0 < CDIM; k0 += 64) {
        __syncthreads();
#pragma unroll
        for (int it = 0; it < 4; ++it)
            *(short8*)&a_lds[ar + 32 * it][ag] = apre[it];
#pragma unroll
        for (int it = 0; it < 8; ++it) {
            short4v h;
            h.x = f2bf(bpre[it].x); h.y = f2bf(bpre[it].y);
            h.z = f2bf(bpre[it].z); h.w = f2bf(bpre[it].w);
            *(short4v*)&b_lds[br + 16 * it][bg] = h;
        }
        __syncthreads();
        if (k0 + 64 < CDIM) {
#pragma unroll
            for (int it = 0; it < 4; ++it)
                apre[it] = *(const short8*)(aptr + (size_t)(32 * it) * CDIM + k0 + 64);
#pragma unroll
            for (int it = 0; it < 8; ++it)
                bpre[it] = *(const float4*)(bptr + (size_t)(16 * it) * CDIM + k0 + 64);
        }

#pragma unroll
        for (int kk = 0; kk < 2; ++kk) {
            short8 af[4], bfr[4];
#pragma unroll
            for (int i = 0; i < 4; ++i)
                af[i] = *(const short8*)&a_lds[wr * 64 + i * 16 + l15][kk * 32 + l4 * 8];
#pragma unroll
            for (int j = 0; j < 4; ++j)
                bfr[j] = *(const short8*)&b_lds[wc * 64 + j * 16 + l15][kk * 32 + l4 * 8];
#pragma unroll
            for (int i = 0; i < 4; ++i)
#pragma unroll
                for (int j = 0; j < 4; ++j)
                    acc[i][j] = mfma16(af[i], bfr[j], acc[i][j]);
        }
    }

    if (which < 2) {
        short* dst = which == 0 ? qws : kws;
        const float scale = which == 0 ? SCALE_Q : 1.0f;
#pragma unroll
        for (int i = 0; i < 4; ++i) {
            int mrow = mbase + wr * 64 + i * 16 + l4 * 4;
#pragma unroll
            for (int j = 0; j < 4; ++j) {
                int o = nbase + wc * 64 + j * 16 + l15;
                int n = o >> 6, d = o & 63;
                float bval = bias[o];
#pragma unroll
                for (int r = 0; r < 4; ++r) {
                    int mm = mrow + r;
                    int bb = mm >> 11;
                    int t = mm & (TSEQ - 1);
                    dst[(((size_t)bb * NHEADS + n) * TSEQ + t) * DHEAD + d] =
                        f2bf((acc[i][j][r] + bval) * scale);
                }
            }
        }
    } else {
#pragma unroll
        for (int i = 0; i < 4; ++i) {
            int mrow = mbase + wr * 64 + i * 16 + l4 * 4;
            int bb = mrow >> 11;
            int t = mrow & (TSEQ - 1);
#pragma unroll
            for (int j = 0; j < 4; ++j) {
                int o = nbase + wc * 64 + j * 16 + l15;
                int n = o >> 6, d = o & 63;
                float bval = bias[o];
                short4v h4;
#pragma unroll
                for (int r = 0; r < 4; ++r) h4[r] = f2bf(acc[i][j][r] + bval);
                *(short4v*)&vtws[(((size_t)bb * NHEADS + n) * DHEAD + d) * TSEQ + t] = h4;
            }
        }
    }
}

// ---------------------------------------------------------------------------
// Output projection GEMM, gl_lds path (frozen from r22).
// ---------------------------------------------------------------------------
__global__ __launch_bounds__(256) void gemm_p_g(
    const short* __restrict__ attn, const short* __restrict__ wpb,
    const float* __restrict__ bp, float* __restrict__ out) {
    __shared__ __attribute__((aligned(16))) short a_lds[64 * 64];
    __shared__ __attribute__((aligned(16))) short b_lds[128 * 64];

    const int tid = threadIdx.x;
    const int lane = tid & 63;
    const int wv = tid >> 6;
    const int wr = wv >> 1, wc = wv & 1;
    const int l15 = lane & 15, l4 = lane >> 4;
    const int mbase = blockIdx.x * 64;
    const int nbase = blockIdx.y * 128;

    f32x4 acc[2][4];
#pragma unroll
    for (int i = 0; i < 2; ++i)
#pragma unroll
        for (int j = 0; j < 4; ++j) acc[i][j] = f32x4{0.f, 0.f, 0.f, 0.f};

    const int srow = tid >> 3;
    const int gcol = (tid & 7) ^ (srow & 7);
    const short* asrc = attn + (size_t)(mbase + srow) * CDIM + gcol * 8;
    const short* bsrc = wpb + (size_t)(nbase + srow) * CDIM + gcol * 8;
    short* adst = &a_lds[tid * 8];
    short* bdst = &b_lds[tid * 8];

    for (int k0 = 0; k0 < CDIM; k0 += 64) {
        __syncthreads();
#pragma unroll
        for (int it = 0; it < 2; ++it)
            gl_lds16(asrc + (size_t)(it * 32) * CDIM + k0, adst + it * 2048);
#pragma unroll
        for (int it = 0; it < 4; ++it)
            gl_lds16(bsrc + (size_t)(it * 32) * CDIM + k0, bdst + it * 2048);
        __syncthreads();

#pragma unroll
        for (int kk = 0; kk < 2; ++kk) {
            short8 af[2], bfr[4];
#pragma unroll
            for (int i = 0; i < 2; ++i) {
                int R = wr * 32 + i * 16 + l15;
                af[i] = *(const short8*)&a_lds[R * 64 + ((kk * 4 + l4) ^ (R & 7)) * 8];
            }
#pragma unroll
            for (int j = 0; j < 4; ++j) {
                int R = wc * 64 + j * 16 + l15;
                bfr[j] = *(const short8*)&b_lds[R * 64 + ((kk * 4 + l4) ^ (R & 7)) * 8];
            }
#pragma unroll
            for (int i = 0; i < 2; ++i)
#pragma unroll
                for (int j = 0; j < 4; ++j)
                    acc[i][j] = mfma16(af[i], bfr[j], acc[i][j]);
        }
    }

#pragma unroll
    for (int i = 0; i < 2; ++i) {
        int mrow = mbase + wr * 32 + i * 16 + l4 * 4;
#pragma unroll
        for (int j = 0; j < 4; ++j) {
            int o = nbase + wc * 64 + j * 16 + l15;
            float bval = bp[o];
#pragma unroll
            for (int r = 0; r < 4; ++r)
                out[(size_t)(mrow + r) * CDIM + o] = acc[i][j][r] + bval;
        }
    }
}

// ---------------------------------------------------------------------------
// Output projection GEMM, fallback (r18-proven): reg staging, bf16 wpb.
// ---------------------------------------------------------------------------
__global__ __launch_bounds__(256) void gemm_p(
    const short* __restrict__ attn, const short* __restrict__ wpb,
    const float* __restrict__ bp, float* __restrict__ out) {
    __shared__ __attribute__((aligned(16))) short a_lds[64][40];
    __shared__ __attribute__((aligned(16))) short b_lds[128][40];

    const int tid = threadIdx.x;
    const int lane = tid & 63;
    const int wv = tid >> 6;
    const int wr = wv >> 1, wc = wv & 1;
    const int l15 = lane & 15, l4 = lane >> 4;
    const int mbase = blockIdx.x * 64;
    const int nbase = blockIdx.y * 128;

    f32x4 acc[2][4];
#pragma unroll
    for (int i = 0; i < 2; ++i)
#pragma unroll
        for (int j = 0; j < 4; ++j) acc[i][j] = f32x4{0.f, 0.f, 0.f, 0.f};

    const int arow = tid >> 2;
    const int acol = (tid & 3) * 8;
    const short* aptr = attn + (size_t)(mbase + arow) * CDIM + acol;
    const short* bptr = wpb + (size_t)(nbase + arow) * CDIM + acol;

    short8 apre, bpre[2];
    apre = *(const short8*)(aptr);
    bpre[0] = *(const short8*)(bptr);
    bpre[1] = *(const short8*)(bptr + (size_t)64 * CDIM);

    for (int k0 = 0; k0 < CDIM; k0 += 32) {
        __syncthreads();
        *(short8*)&a_lds[arow][acol] = apre;
        *(short8*)&b_lds[arow][acol] = bpre[0];
        *(short8*)&b_lds[arow + 64][acol] = bpre[1];
        __syncthreads();
        if (k0 + 32 < CDIM) {
            apre = *(const short8*)(aptr + k0 + 32);
            bpre[0] = *(const short8*)(bptr + k0 + 32);
            bpre[1] = *(const short8*)(bptr + (size_t)64 * CDIM + k0 + 32);
        }

        short8 af[2], bfr[4];
#pragma unroll
        for (int i = 0; i < 2; ++i)
            af[i] = *(const short8*)&a_lds[wr * 32 + i * 16 + l15][l4 * 8];
#pragma unroll
        for (int j = 0; j < 4; ++j)
            bfr[j] = *(const short8*)&b_lds[wc * 64 + j * 16 + l15][l4 * 8];
#pragma unroll
        for (int i = 0; i < 2; ++i)
#pragma unroll
            for (int j = 0; j < 4; ++j)
                acc[i][j] = mfma16(af[i], bfr[j], acc[i][j]);
    }

#pragma unroll
    for (int i = 0; i < 2; ++i) {
        int mrow = mbase + wr * 32 + i * 16 + l4 * 4;
#pragma unroll
        for (int j = 0; j < 4; ++j) {
            int o = nbase + wc * 64 + j * 16 + l15;
            float bval = bp[o];
#pragma unroll
            for (int r = 0; r < 4; ++r)
                out[(size_t)(mrow + r) * CDIM + o] = acc[i][j][r] + bval;
        }
    }
}

// ---------------------------------------------------------------------------
// Flash attention v8 (best-measured): QBLK=64 (4 waves x 16 q-rows),
// KVBLK=128, no-max softmax via native exp2 (q pre-scaled), l via ones-row
// MFMA, truncated bf16 P, setprio around MFMA clusters, hoisted wave-uniform
// causal-mask branch, K/V reg-prefetch into XOR-swizzled LDS.
// ---------------------------------------------------------------------------
__global__ __launch_bounds__(256) void attn_kernel(
    const short* __restrict__ q, const short* __restrict__ k,
    const short* __restrict__ vt, short* __restrict__ attn_out) {
    __shared__ __attribute__((aligned(16))) short k_lds[128][64];
    __shared__ __attribute__((aligned(16))) short vt_lds[64][128];
    __shared__ __attribute__((aligned(16))) short p_lds[4][16][136];

    const int tid = threadIdx.x;
    const int w = tid >> 6;
    const int lane = tid & 63;
    const int l15 = lane & 15;
    const int l4 = lane >> 4;
    const int h = blockIdx.x;
    const int qtile = gridDim.y - 1 - blockIdx.y;
    const int wrow0 = qtile * 64 + w * 16;

    short8 qf[2];
#pragma unroll
    for (int kh = 0; kh < 2; ++kh)
        qf[kh] = *(const short8*)(q + ((size_t)h * TSEQ + wrow0 + l15) * DHEAD +
                                  kh * 32 + l4 * 8);

    const short onebf = (short)0x3F80;  // bf16(1.0)
    short8 vf_ones;
#pragma unroll
    for (int e = 0; e < 8; ++e) vf_ones[e] = (l15 == 0) ? onebf : (short)0;

    f32x4 o_acc[4];
    f32x4 o5 = f32x4{0.f, 0.f, 0.f, 0.f};
#pragma unroll
    for (int dt = 0; dt < 4; ++dt) o_acc[dt] = f32x4{0.f, 0.f, 0.f, 0.f};

    const int ntiles = (qtile + 2) >> 1;
    const size_t kbase = (size_t)h * TSEQ * DHEAD;
    const size_t vbase = (size_t)h * DHEAD * TSEQ;

    const int ksrow = tid >> 3, ksg = tid & 7;
    const int vsrow = tid >> 4, vsg = tid & 15;

    short8 kpre[4], vpre[4];
#pragma unroll
    for (int it = 0; it < 4; ++it) {
        kpre[it] = *(const short8*)(k + kbase + (size_t)(ksrow + it * 32) * DHEAD + ksg * 8);
        vpre[it] = *(const short8*)(vt + vbase + (size_t)(vsrow + it * 16) * TSEQ + vsg * 8);
    }

    for (int kvt = 0; kvt < ntiles; ++kvt) {
        const int kvbase = kvt * 128;
        __syncthreads();
#pragma unroll
        for (int it = 0; it < 4; ++it) {
            int krow = ksrow + it * 32;
            *(short8*)&k_lds[krow][(ksg ^ (krow & 7)) * 8] = kpre[it];
            int vrow = vsrow + it * 16;
            *(short8*)&vt_lds[vrow][((vsg ^ (vrow & 15))) * 8] = vpre[it];
        }
        __syncthreads();
        if (kvt + 1 < ntiles) {
            int kvb2 = kvbase + 128;
#pragma unroll
            for (int it = 0; it < 4; ++it) {
                kpre[it] = *(const short8*)(k + kbase + (size_t)(kvb2 + ksrow + it * 32) * DHEAD + ksg * 8);
                vpre[it] = *(const short8*)(vt + vbase + (size_t)(vsrow + it * 16) * TSEQ + kvb2 + vsg * 8);
            }
        }

        f32x4 s[8];
        __builtin_amdgcn_s_setprio(1);
#pragma unroll
        for (int jt = 0; jt < 8; ++jt) {
            int row = jt * 16 + l15;
            int sw = row & 7;
            short8 kf0 = *(const short8*)&k_lds[row][(l4 ^ sw) * 8];
            short8 kf1 = *(const short8*)&k_lds[row][((4 + l4) ^ sw) * 8];
            f32x4 a = f32x4{0.f, 0.f, 0.f, 0.f};
            a = mfma16(qf[0], kf0, a);
            a = mfma16(qf[1], kf1, a);
            s[jt] = a;
        }
        __builtin_amdgcn_s_setprio(0);

        // softmax: p = native exp2(s); truncated bf16 store.
        // Wave-uniform mask branch: only the diagonal tile pays mask cost.
        if (kvbase + 127 > wrow0) {
#pragma unroll
            for (int r = 0; r < 4; ++r) {
                int qrow = wrow0 + l4 * 4 + r;
#pragma unroll
                for (int jt = 0; jt < 8; ++jt) {
                    float x = s[jt][r];
                    if (kvbase + jt * 16 + l15 > qrow) x = -INFINITY;
                    unsigned int eb = __builtin_bit_cast(unsigned int,
                                                         __builtin_amdgcn_exp2f(x));
                    p_lds[w][l4 * 4 + r][jt * 16 + l15] = (short)(eb >> 16);
                }
            }
        } else {
#pragma unroll
            for (int r = 0; r < 4; ++r) {
#pragma unroll
                for (int jt = 0; jt < 8; ++jt) {
                    unsigned int eb = __builtin_bit_cast(unsigned int,
                                                         __builtin_amdgcn_exp2f(s[jt][r]));
                    p_lds[w][l4 * 4 + r][jt * 16 + l15] = (short)(eb >> 16);
                }
            }
        }

        short8 pa[4];
#pragma unroll
        for (int ks = 0; ks < 4; ++ks)
            pa[ks] = *(const short8*)&p_lds[w][l15][ks * 32 + l4 * 8];
        __builtin_amdgcn_s_setprio(1);
#pragma unroll
        for (int dt = 0; dt < 4; ++dt) {
            int row = dt * 16 + l15;
            int sw = row & 15;
#pragma unroll
            for (int ks = 0; ks < 4; ++ks) {
                short8 vf = *(const short8*)&vt_lds[row][((ks * 4 + l4) ^ sw) * 8];
                o_acc[dt] = mfma16(pa[ks], vf, o_acc[dt]);
            }
        }
#pragma unroll
        for (int ks = 0; ks < 4; ++ks)
            o5 = mfma16(pa[ks], vf_ones, o5);
        __builtin_amdgcn_s_setprio(0);
    }

    float inv[4];
#pragma unroll
    for (int r = 0; r < 4; ++r)
        inv[r] = 1.0f / __shfl(o5[r], lane & 48);
    const int b = h >> 4, n = h & 15;
#pragma unroll
    for (int dt = 0; dt < 4; ++dt) {
#pragma unroll
        for (int r = 0; r < 4; ++r) {
            int t = wrow0 + l4 * 4 + r;
            attn_out[((size_t)b * TSEQ + t) * CDIM + n * DHEAD + dt * 16 + l15] =
                f2bf(o_acc[dt][r] * inv[r]);
        }
    }
}

extern "C" void kernel_launch(void* const* d_in, const int* in_sizes, int n_in,
                              void* d_out, int out_size, void* d_ws, size_t ws_size,
                              hipStream_t stream) {
    const float* x  = (const float*)d_in[0];
    const float* Wq = (const float*)d_in[1];
    const float* bq = (const float*)d_in[2];
    const float* Wk = (const float*)d_in[3];
    const float* bk = (const float*)d_in[4];
    const float* Wv = (const float*)d_in[5];
    const float* bv = (const float*)d_in[6];
    const float* Wp = (const float*)d_in[7];
    const float* bp = (const float*)d_in[8];

    char* ws = (char*)d_ws;
    const size_t SZ = (size_t)MROWS * CDIM * sizeof(short);  // 8 MB
    const size_t WSZ = (size_t)CDIM * CDIM * sizeof(short);  // 2 MB
    short* qws  = (short*)(ws);
    short* kws  = (short*)(ws + SZ);
    short* vtws = (short*)(ws + 2 * SZ);
    short* xb   = (short*)(ws + 3 * SZ);
    short* attn = xb;  // alias: xb dead after QKV GEMM

    if (ws_size >= 4 * SZ + 4 * WSZ) {
        short* wqb = (short*)(ws + 4 * SZ);
        short* wkb = wqb + (size_t)CDIM * CDIM;
        short* wvb = wkb + (size_t)CDIM * CDIM;
        short* wpb = wvb + (size_t)CDIM * CDIM;
        conv5_kernel<<<4096, 256, 0, stream>>>(x, Wq, Wk, Wv, Wp,
                                               xb, wqb, wkb, wvb, wpb);
        gemm_qkv_g<<<dim3(MROWS / 128, 24), 256, 0, stream>>>(
            xb, wqb, wkb, wvb, bq, bk, bv, qws, kws, vtws);
        attn_kernel<<<dim3(BSZ * NHEADS, TSEQ / 64), 256, 0, stream>>>(qws, kws, vtws, attn);
        gemm_p_g<<<dim3(MROWS / 64, CDIM / 128), 256, 0, stream>>>(attn, wpb, bp, (float*)d_out);
    } else {
        short* wpb = qws;  // alias: qws dead after attn
        convx_kernel<<<2048, 256, 0, stream>>>(x, xb);
        gemm_qkv<<<dim3(MROWS / 128, 24), 256, 0, stream>>>(
            xb, Wq, Wk, Wv, bq, bk, bv, qws, kws, vtws);
        attn_kernel<<<dim3(BSZ * NHEADS, TSEQ / 64), 256, 0, stream>>>(qws, kws, vtws, attn);
        convx_kernel<<<512, 256, 0, stream>>>(Wp, wpb);
        gemm_p<<<dim3(MROWS / 64, CDIM / 128), 256, 0, stream>>>(attn, wpb, bp, (float*)d_out);
    }
}